// Round 2
// baseline (1054.374 us; speedup 1.0000x reference)
//
#include <hip/hip_runtime.h>

// VQBlock: x[16,64,64,256] fp32, dict[256,1024] fp32.
// out = concat(q_st flat [16777216], loss [1]) fp32.
//
// Round 2: match the np-fp32 reference bit-semantics on ambiguous rows.
//  - fast path: fp32 register-tiled scan of s_k = ||d_k||^2 - 2 f.d_k,
//    block = 64 rows x 1024 codes, thread = 8 rows x 4 codes, top-2 per row
//  - rows with top-2 gap < 2e-3 (~0.5%): full 1024-code rescan computing the
//    REFERENCE-style fp32 distance fl(fl(nf+nd_k) - fl(2*sim_k)) with
//      nf  = pairwise fp32 sum of x^2 (order-insensitive by shift-invariance)
//      nd_k= sequential non-FMA fp32 adds of fl(d^2), d ascending (np axis-0 reduce)
//      sim_k= single-chain sequential FMA, d ascending (BLAS sgemm microkernel)
//    argmin with first-index tie-break (np.argmin semantics)
//  - loss: per-block fp32 partials -> fp64 deterministic reduce

#define NROWS   65536
#define DIM     256
#define NCODE   1024
#define RPB     64          // rows per block
#define FSTRIDE 68          // padded LDS row stride (conflict-free, 16B-aligned)
#define EPS_TIE 2e-3f

// ---------- pre-kernels ----------

__global__ void k_transpose(const float* __restrict__ dict, float* __restrict__ dictT) {
    int t = blockIdx.x * 256 + threadIdx.x;          // grid 256 x 256
#pragma unroll
    for (int i = 0; i < 4; ++i) {
        int e = i * 65536 + t;                        // coalesced read
        int d = e >> 10, k = e & 1023;
        dictT[k * DIM + d] = dict[e];
    }
}

__global__ void k_norms(const float* __restrict__ dict, float* __restrict__ dictnorm) {
    int k = blockIdx.x * 256 + threadIdx.x;           // grid 4 x 256
    float s = 0.f;
#pragma unroll 8
    for (int d = 0; d < DIM; ++d) {
        float v = dict[d * NCODE + k];                // coalesced across k
        s = fmaf(v, v, s);
    }
    dictnorm[k] = s;
}

// np pairwise sum of squares of 128 strided elements (numpy pairwise_sum pattern)
__device__ __forceinline__ float np_pairwise_sq_128(const float* a, int stride) {
    float r[8];
#pragma unroll
    for (int j = 0; j < 8; ++j) {
        float v = a[j * stride];
        r[j] = __fmul_rn(v, v);
    }
    for (int i = 8; i < 128; i += 8) {
#pragma unroll
        for (int j = 0; j < 8; ++j) {
            float v = a[(i + j) * stride];
            r[j] = __fadd_rn(r[j], __fmul_rn(v, v));
        }
    }
    return __fadd_rn(__fadd_rn(__fadd_rn(r[0], r[1]), __fadd_rn(r[2], r[3])),
                     __fadd_rn(__fadd_rn(r[4], r[5]), __fadd_rn(r[6], r[7])));
}

// ---------- main kernel ----------

__global__ __launch_bounds__(256, 2) void k_vq(
    const float* __restrict__ x, const float* __restrict__ dict,
    const float* __restrict__ dictT, const float* __restrict__ dictnorm,
    float* __restrict__ out, double* __restrict__ block_sums)
{
    __shared__ __align__(16) float f_t[DIM * FSTRIDE];   // x tile, transposed [d][row]
    __shared__ float row_m1[RPB], row_m2[RPB];
    __shared__ int   row_k1[RPB];
    __shared__ float wred[4];
    __shared__ float red_d[256];
    __shared__ int   red_k[256];
    __shared__ int   amb_list[RPB];
    __shared__ int   amb_cnt;

    const int tid  = threadIdx.x;
    const int row0 = blockIdx.x * RPB;

    if (tid == 0) amb_cnt = 0;

    // stage x tile (coalesced global, transposed into LDS)
    {
        const int d = tid;
        const float* xp = x + (size_t)row0 * DIM + d;
#pragma unroll 4
        for (int r = 0; r < RPB; ++r)
            f_t[d * FSTRIDE + r] = xp[(size_t)r * DIM];
    }
    __syncthreads();

    const int tc = tid & 31, tr = tid >> 5;
    const int rbase = tr * 8;

    float m1[8], m2[8]; int j1[8], j2[8];
#pragma unroll
    for (int r = 0; r < 8; ++r) { m1[r] = 3.0e38f; m2[r] = 3.0e38f; j1[r] = 0x7fffffff; j2[r] = 0x7fffffff; }

    for (int kc = 0; kc < 8; ++kc) {
        const int kb = kc * 128 + tc * 4;
        float acc[8][4];
#pragma unroll
        for (int r = 0; r < 8; ++r) { acc[r][0] = 0.f; acc[r][1] = 0.f; acc[r][2] = 0.f; acc[r][3] = 0.f; }

        const float* dp = dict + kb;
#pragma unroll 4
        for (int d = 0; d < DIM; ++d) {
            const float4 dv = *(const float4*)(dp + (size_t)d * NCODE);       // L2-resident dict
            const float4 fa = *(const float4*)&f_t[d * FSTRIDE + rbase];      // broadcast, no conflict
            const float4 fb = *(const float4*)&f_t[d * FSTRIDE + rbase + 4];
            const float fr[8] = { fa.x, fa.y, fa.z, fa.w, fb.x, fb.y, fb.z, fb.w };
#pragma unroll
            for (int r = 0; r < 8; ++r) {
                acc[r][0] = fmaf(fr[r], dv.x, acc[r][0]);
                acc[r][1] = fmaf(fr[r], dv.y, acc[r][1]);
                acc[r][2] = fmaf(fr[r], dv.z, acc[r][2]);
                acc[r][3] = fmaf(fr[r], dv.w, acc[r][3]);
            }
        }

        const float4 dn4 = *(const float4*)&dictnorm[kb];
        const float dn[4] = { dn4.x, dn4.y, dn4.z, dn4.w };
#pragma unroll
        for (int c = 0; c < 4; ++c) {
            const int k = kb + c;
#pragma unroll
            for (int r = 0; r < 8; ++r) {
                const float s = dn[c] - 2.f * acc[r][c];
                if (s < m1[r])      { m2[r] = m1[r]; j2[r] = j1[r]; m1[r] = s; j1[r] = k; }
                else if (s < m2[r]) { m2[r] = s; j2[r] = k; }
            }
        }
    }

    // cross-lane top-2 merge over the 32 code-threads sharing each row
#pragma unroll
    for (int r = 0; r < 8; ++r) {
        float a1 = m1[r], a2 = m2[r]; int b1 = j1[r], b2 = j2[r];
#pragma unroll
        for (int sft = 1; sft < 32; sft <<= 1) {
            float o1 = __shfl_xor(a1, sft, 32);
            float o2 = __shfl_xor(a2, sft, 32);
            int   p1 = __shfl_xor(b1, sft, 32);
            int   p2 = __shfl_xor(b2, sft, 32);
            if (o1 < a1 || (o1 == a1 && p1 < b1)) {
                bool t = (a1 < o2) || (a1 == o2 && b1 < p2);
                a2 = t ? a1 : o2; b2 = t ? b1 : p2;
                a1 = o1; b1 = p1;
            } else {
                bool t = (o1 < a2) || (o1 == a2 && p1 < b2);
                a2 = t ? o1 : a2; b2 = t ? p1 : b2;
            }
        }
        if (tc == 0) {
            row_m1[rbase + r] = a1; row_m2[rbase + r] = a2;
            row_k1[rbase + r] = b1;
        }
    }
    __syncthreads();

    // flag ambiguous rows (top-2 gap below quantization safety margin)
    if (tid < RPB && (row_m2[tid] - row_m1[tid]) < EPS_TIE) {
        int p = atomicAdd(&amb_cnt, 1);
        amb_list[p] = tid;
    }
    __syncthreads();

    // np-fp32-faithful full rescan of ambiguous rows (~0.34 rows/block avg)
    for (int a = 0; a < amb_cnt; ++a) {
        const int r = amb_list[a];
        // nf: pairwise fp32 sum of x^2 (exact order irrelevant by shift-invariance,
        // but use the np pairwise pattern anyway)
        const float nf = __fadd_rn(np_pairwise_sq_128(&f_t[r], FSTRIDE),
                                   np_pairwise_sq_128(&f_t[128 * FSTRIDE + r], FSTRIDE));
        float bd = 3.4e38f; int bk = 0x7fffffff;
#pragma unroll
        for (int i = 0; i < 4; ++i) {
            const int k = i * 256 + tid;                  // coalesced dict reads
            float sim = 0.f, nd = 0.f;
            for (int d = 0; d < DIM; ++d) {
                const float dv = dict[(size_t)d * NCODE + k];
                const float fv = f_t[d * FSTRIDE + r];
                sim = fmaf(fv, dv, sim);                   // BLAS: single FMA chain, d asc
                nd  = __fadd_rn(nd, __fmul_rn(dv, dv));    // np axis-0 reduce: seq non-FMA
            }
            const float dist = __fsub_rn(__fadd_rn(nf, nd), __fmul_rn(2.f, sim));
            if (dist < bd) { bd = dist; bk = k; }          // k ascending: first-min kept
        }
        red_d[tid] = bd; red_k[tid] = bk;
        __syncthreads();
        for (int s = 128; s > 0; s >>= 1) {
            if (tid < s) {
                const float od = red_d[tid + s]; const int ok = red_k[tid + s];
                if (od < red_d[tid] || (od == red_d[tid] && ok < red_k[tid])) {
                    red_d[tid] = od; red_k[tid] = ok;
                }
            }
            __syncthreads();
        }
        if (tid == 0) row_k1[r] = red_k[0];
        __syncthreads();
    }

    // gather q = 0.5*dictT[kstar], write out (coalesced), accumulate loss
    float lsum = 0.f;
#pragma unroll 2
    for (int i = 0; i < 16; ++i) {
        const int e = i * 1024 + tid * 4;
        const int r = e >> 8, d0 = e & 255;
        const int kk = row_k1[r];
        const float4 dv = *(const float4*)&dictT[(size_t)kk * DIM + d0];
        float4 q; q.x = 0.5f * dv.x; q.y = 0.5f * dv.y; q.z = 0.5f * dv.z; q.w = 0.5f * dv.w;
        const float x0 = f_t[(d0 + 0) * FSTRIDE + r];
        const float x1 = f_t[(d0 + 1) * FSTRIDE + r];
        const float x2 = f_t[(d0 + 2) * FSTRIDE + r];
        const float x3 = f_t[(d0 + 3) * FSTRIDE + r];
        const float e0 = x0 - q.x, e1 = x1 - q.y, e2 = x2 - q.z, e3 = x3 - q.w;
        lsum += e0 * e0 + e1 * e1 + e2 * e2 + e3 * e3;
        *(float4*)&out[(size_t)row0 * DIM + e] = q;
    }

    // deterministic block reduction of loss partial
#pragma unroll
    for (int sft = 32; sft > 0; sft >>= 1) lsum += __shfl_down(lsum, sft, 64);
    if ((tid & 63) == 0) wred[tid >> 6] = lsum;
    __syncthreads();
    if (tid == 0)
        block_sums[blockIdx.x] = (double)((wred[0] + wred[1]) + (wred[2] + wred[3]));
}

// ---------- loss finalize (deterministic fp64 reduce of 1024 partials) ----------

__global__ void k_finalize(const double* __restrict__ block_sums, float* __restrict__ out_loss) {
    __shared__ double w[16];
    const int t = threadIdx.x;                  // 1024 threads
    double v = block_sums[t];
#pragma unroll
    for (int sft = 32; sft > 0; sft >>= 1) v += __shfl_down(v, sft, 64);
    if ((t & 63) == 0) w[t >> 6] = v;
    __syncthreads();
    if (t == 0) {
        double tot = 0.0;
        for (int i = 0; i < 16; ++i) tot += w[i];
        // loss = dict_loss + 0.25*commit_loss = 1.25 * mean((x-q)^2)
        out_loss[0] = (float)(1.25 * tot / (double)(NROWS * DIM));
    }
}

// ---------- launch ----------

extern "C" void kernel_launch(void* const* d_in, const int* in_sizes, int n_in,
                              void* d_out, int out_size, void* d_ws, size_t ws_size,
                              hipStream_t stream) {
    (void)in_sizes; (void)n_in; (void)out_size; (void)ws_size;
    const float* x    = (const float*)d_in[0];
    const float* dict = (const float*)d_in[1];
    float* out = (float*)d_out;

    char* ws = (char*)d_ws;
    float*  dictT      = (float*)ws;                                          // 1 MB
    float*  dictnorm   = (float*)(ws + (size_t)NCODE * DIM * 4);              // 4 KB
    double* block_sums = (double*)(ws + (size_t)NCODE * DIM * 4 + NCODE * 4); // 8 KB

    k_transpose<<<256, 256, 0, stream>>>(dict, dictT);
    k_norms<<<4, 256, 0, stream>>>(dict, dictnorm);
    k_vq<<<NROWS / RPB, 256, 0, stream>>>(x, dict, dictT, dictnorm, out, block_sums);
    k_finalize<<<1, 1024, 0, stream>>>(block_sums, out + (size_t)NROWS * DIM);
}

// Round 3
// 306.995 us; speedup vs baseline: 3.4345x; 3.4345x over previous
//
#include <hip/hip_runtime.h>

// VQBlock: x[16,64,64,256] fp32, dict[256,1024] fp32.
// out = concat(q_st flat [16777216], loss [1]) fp32.
//
// Round 3: f16 MFMA fast path (16x16x32_f16), proven np-faithful fp32 rescan
// for rows with fast top-2 gap < EPS_TIE (~1%). Fast-path distance error
// sigma ~3e-4 << EPS_TIE=4e-3 (8.9 sigma). q_st written as fl(x + fl(q-x))
// to match np exactly.

#define NROWS   65536
#define DIM     256
#define NCODE   1024
#define RPB     64
#define EPS_TIE 4e-3f

typedef _Float16 half8 __attribute__((ext_vector_type(8)));
typedef float    f32x4 __attribute__((ext_vector_type(4)));

// ---------- pre-kernels ----------

__global__ void k_transpose(const float* __restrict__ dict, float* __restrict__ dictT) {
    int t = blockIdx.x * 256 + threadIdx.x;          // grid 256 x 256
#pragma unroll
    for (int i = 0; i < 4; ++i) {
        int e = i * 65536 + t;                        // coalesced read
        int d = e >> 10, k = e & 1023;
        dictT[k * DIM + d] = dict[e];
    }
}

__global__ void k_norms(const float* __restrict__ dict, float* __restrict__ dictnorm) {
    int k = blockIdx.x * 256 + threadIdx.x;           // grid 4 x 256
    float s = 0.f;
#pragma unroll 8
    for (int d = 0; d < DIM; ++d) {
        float v = dict[d * NCODE + k];
        s = fmaf(v, v, s);
    }
    dictnorm[k] = s;
}

// pack dict -> f16 MFMA-B layout: packB[kk*32768 + n*32 + q*8 + j] = f16(dict[(kk*32+q*8+j)][n])
__global__ void k_pack(const float* __restrict__ dict, unsigned short* __restrict__ packB) {
    int gid = blockIdx.x * 256 + threadIdx.x;         // grid 256 x 256
#pragma unroll
    for (int ii = 0; ii < 4; ++ii) {
        int o = ii * 65536 + gid;                     // coalesced write
        int j = o & 7, q = (o >> 3) & 3, n = (o >> 5) & 1023, kk = o >> 15;
        int d = kk * 32 + q * 8 + j;
        _Float16 h = (_Float16)dict[d * NCODE + n];   // RTN cvt
        packB[o] = *(unsigned short*)&h;
    }
}

// np pairwise sum of squares of 128 strided elements
__device__ __forceinline__ float np_pairwise_sq_128(const float* a, int stride) {
    float r[8];
#pragma unroll
    for (int j = 0; j < 8; ++j) {
        float v = a[j * stride];
        r[j] = __fmul_rn(v, v);
    }
    for (int i = 8; i < 128; i += 8) {
#pragma unroll
        for (int j = 0; j < 8; ++j) {
            float v = a[(i + j) * stride];
            r[j] = __fadd_rn(r[j], __fmul_rn(v, v));
        }
    }
    return __fadd_rn(__fadd_rn(__fadd_rn(r[0], r[1]), __fadd_rn(r[2], r[3])),
                     __fadd_rn(__fadd_rn(r[4], r[5]), __fadd_rn(r[6], r[7])));
}

// ---------- main kernel ----------

__global__ __launch_bounds__(256, 4) void k_vq(
    const float* __restrict__ x, const float* __restrict__ dict,
    const float* __restrict__ dictT, const float* __restrict__ dictnorm,
    const unsigned short* __restrict__ packB,
    float* __restrict__ out, double* __restrict__ block_sums)
{
    __shared__ __align__(16) unsigned short bstage[8 * 2048];  // 32 KB: [kk][n_local*32 + q*8 + j]
    __shared__ float row_m1[RPB], row_m2[RPB];
    __shared__ int   row_k1[RPB], row_k2[RPB];
    __shared__ float red_d[256];
    __shared__ int   red_k[256];
    __shared__ float wred[4];
    __shared__ int   amb_list[RPB];
    __shared__ int   amb_cnt;

    const int tid  = threadIdx.x;
    const int ln   = tid & 63, wv = tid >> 6;
    const int l15  = ln & 15, q = ln >> 4;
    const int row0 = blockIdx.x * RPB;

    if (tid == 0) amb_cnt = 0;

    // A fragments (register-resident, reused over all 16 chunks):
    // lane provides A row m=l15 (x row row0 + wv*16 + l15), k = kk*32 + q*8 + j
    half8 afrag[8];
    {
        const float* ar = x + (size_t)(row0 + wv * 16 + l15) * DIM + q * 8;
#pragma unroll
        for (int kk = 0; kk < 8; ++kk) {
            const float4 p0 = *(const float4*)(ar + kk * 32);
            const float4 p1 = *(const float4*)(ar + kk * 32 + 4);
            half8 h;
            h[0] = (_Float16)p0.x; h[1] = (_Float16)p0.y; h[2] = (_Float16)p0.z; h[3] = (_Float16)p0.w;
            h[4] = (_Float16)p1.x; h[5] = (_Float16)p1.y; h[6] = (_Float16)p1.z; h[7] = (_Float16)p1.w;
            afrag[kk] = h;
        }
    }

    // per-lane top-2 for its 4 C-rows (local rows q*4+i)
    float m1[4], m2[4]; int j1[4], j2[4];
#pragma unroll
    for (int i = 0; i < 4; ++i) { m1[i] = 3.0e38f; m2[i] = 3.0e38f; j1[i] = 0x7fffffff; j2[i] = 0x7fffffff; }

    for (int cc = 0; cc < 16; ++cc) {
        const int c0 = cc * 64;
        __syncthreads();                               // protect bstage from readers of prev chunk
        {
            const unsigned short* src = packB + (size_t)c0 * 32 + tid * 8;
            uint4 tmp[8];
#pragma unroll
            for (int kk = 0; kk < 8; ++kk) tmp[kk] = *(const uint4*)(src + (size_t)kk * 32768);
#pragma unroll
            for (int kk = 0; kk < 8; ++kk) *(uint4*)&bstage[kk * 2048 + tid * 8] = tmp[kk];
        }
        __syncthreads();

        float dn[4];
#pragma unroll
        for (int t = 0; t < 4; ++t) dn[t] = dictnorm[c0 + t * 16 + l15];

        const f32x4 zero = {0.f, 0.f, 0.f, 0.f};
        f32x4 acc[4];
#pragma unroll
        for (int t = 0; t < 4; ++t) acc[t] = zero;

#pragma unroll
        for (int kk = 0; kk < 8; ++kk) {
#pragma unroll
            for (int t = 0; t < 4; ++t) {              // 4 independent MFMA chains
                const half8 b = *(const half8*)&bstage[kk * 2048 + (t * 16 + l15) * 32 + q * 8];
                acc[t] = __builtin_amdgcn_mfma_f32_16x16x32_f16(afrag[kk], b, acc[t], 0, 0, 0);
            }
        }

#pragma unroll
        for (int t = 0; t < 4; ++t) {
            const int k = c0 + t * 16 + l15;
#pragma unroll
            for (int i = 0; i < 4; ++i) {
                const float s = fmaf(-2.f, acc[t][i], dn[t]);
                if (s < m1[i])      { m2[i] = m1[i]; j2[i] = j1[i]; m1[i] = s; j1[i] = k; }
                else if (s < m2[i]) { m2[i] = s; j2[i] = k; }
            }
        }
    }

    // top-2 merge across the 16 lanes sharing quad q (they hold the same 4 rows)
#pragma unroll
    for (int i = 0; i < 4; ++i) {
        float a1 = m1[i], a2 = m2[i]; int b1 = j1[i], b2 = j2[i];
#pragma unroll
        for (int sft = 1; sft < 16; sft <<= 1) {
            float o1 = __shfl_xor(a1, sft);
            float o2 = __shfl_xor(a2, sft);
            int   p1 = __shfl_xor(b1, sft);
            int   p2 = __shfl_xor(b2, sft);
            if (o1 < a1 || (o1 == a1 && p1 < b1)) {
                bool t = (a1 < o2) || (a1 == o2 && b1 < p2);
                a2 = t ? a1 : o2; b2 = t ? b1 : p2;
                a1 = o1; b1 = p1;
            } else {
                bool t = (o1 < a2) || (o1 == a2 && p1 < b2);
                a2 = t ? o1 : a2; b2 = t ? p1 : b2;
            }
        }
        if (l15 == 0) {
            const int r = wv * 16 + q * 4 + i;
            row_m1[r] = a1; row_m2[r] = a2; row_k1[r] = b1; row_k2[r] = b2;
        }
    }
    __syncthreads();

    if (tid < RPB && (row_m2[tid] - row_m1[tid]) < EPS_TIE) {
        int p = atomicAdd(&amb_cnt, 1);
        amb_list[p] = tid;
    }
    __syncthreads();
    const int namb = amb_cnt;

    // np-fp32-faithful full rescan of ambiguous rows (proven in round 2)
    for (int a = 0; a < namb; ++a) {
        const int r = amb_list[a];
        const float* xr = x + (size_t)(row0 + r) * DIM;
        const float nf = __fadd_rn(np_pairwise_sq_128(xr, 1), np_pairwise_sq_128(xr + 128, 1));
        float bd = 3.4e38f; int bk = 0x7fffffff;
#pragma unroll
        for (int i = 0; i < 4; ++i) {
            const int k = i * 256 + tid;                  // coalesced dict reads
            float sim = 0.f, nd = 0.f;
            for (int d = 0; d < DIM; ++d) {
                const float dv = dict[(size_t)d * NCODE + k];
                const float fv = xr[d];                    // broadcast (L1)
                sim = fmaf(fv, dv, sim);                   // BLAS-style FMA chain, d asc
                nd  = __fadd_rn(nd, __fmul_rn(dv, dv));    // np axis-0 reduce
            }
            const float dist = __fsub_rn(__fadd_rn(nf, nd), __fmul_rn(2.f, sim));
            if (dist < bd) { bd = dist; bk = k; }
        }
        red_d[tid] = bd; red_k[tid] = bk;
        __syncthreads();
        for (int s = 128; s > 0; s >>= 1) {
            if (tid < s) {
                const float od = red_d[tid + s]; const int ok = red_k[tid + s];
                if (od < red_d[tid] || (od == red_d[tid] && ok < red_k[tid])) {
                    red_d[tid] = od; red_k[tid] = ok;
                }
            }
            __syncthreads();
        }
        if (tid == 0) row_k1[r] = red_k[0];
        __syncthreads();
    }

    // epilogue: q = 0.5*dictT[kstar]; out = fl(x + fl(q-x)) (np-exact); loss partial
    float lsum = 0.f;
#pragma unroll 2
    for (int i = 0; i < 16; ++i) {
        const int e = i * 1024 + tid * 4;
        const int r = e >> 8, d0 = e & 255;
        const int kk = row_k1[r];
        const float4 dv = *(const float4*)&dictT[(size_t)kk * DIM + d0];
        const float4 xv = *(const float4*)&x[(size_t)row0 * DIM + e];
        float4 qv; qv.x = 0.5f * dv.x; qv.y = 0.5f * dv.y; qv.z = 0.5f * dv.z; qv.w = 0.5f * dv.w;
        float4 ov;
        ov.x = __fadd_rn(xv.x, __fsub_rn(qv.x, xv.x));
        ov.y = __fadd_rn(xv.y, __fsub_rn(qv.y, xv.y));
        ov.z = __fadd_rn(xv.z, __fsub_rn(qv.z, xv.z));
        ov.w = __fadd_rn(xv.w, __fsub_rn(qv.w, xv.w));
        const float e0 = __fsub_rn(xv.x, qv.x), e1 = __fsub_rn(xv.y, qv.y);
        const float e2 = __fsub_rn(xv.z, qv.z), e3 = __fsub_rn(xv.w, qv.w);
        lsum += e0 * e0 + e1 * e1 + e2 * e2 + e3 * e3;
        *(float4*)&out[(size_t)row0 * DIM + e] = ov;
    }

#pragma unroll
    for (int sft = 32; sft > 0; sft >>= 1) lsum += __shfl_down(lsum, sft, 64);
    if ((tid & 63) == 0) wred[tid >> 6] = lsum;
    __syncthreads();
    if (tid == 0)
        block_sums[blockIdx.x] = (double)((wred[0] + wred[1]) + (wred[2] + wred[3]));
}

// ---------- loss finalize ----------

__global__ void k_finalize(const double* __restrict__ block_sums, float* __restrict__ out_loss) {
    __shared__ double w[16];
    const int t = threadIdx.x;                  // 1024 threads
    double v = block_sums[t];
#pragma unroll
    for (int sft = 32; sft > 0; sft >>= 1) v += __shfl_down(v, sft, 64);
    if ((t & 63) == 0) w[t >> 6] = v;
    __syncthreads();
    if (t == 0) {
        double tot = 0.0;
        for (int i = 0; i < 16; ++i) tot += w[i];
        out_loss[0] = (float)(1.25 * tot / (double)(NROWS * DIM));
    }
}

// ---------- launch ----------

extern "C" void kernel_launch(void* const* d_in, const int* in_sizes, int n_in,
                              void* d_out, int out_size, void* d_ws, size_t ws_size,
                              hipStream_t stream) {
    (void)in_sizes; (void)n_in; (void)out_size; (void)ws_size;
    const float* x    = (const float*)d_in[0];
    const float* dict = (const float*)d_in[1];
    float* out = (float*)d_out;

    char* ws = (char*)d_ws;
    float*          dictT      = (float*)ws;                          // 1 MB
    float*          dictnorm   = (float*)(ws + 1048576);              // 4 KB
    double*         block_sums = (double*)(ws + 1048576 + 4096);      // 8 KB
    unsigned short* packB      = (unsigned short*)(ws + 1048576 + 4096 + 8192); // 512 KB

    k_transpose<<<256, 256, 0, stream>>>(dict, dictT);
    k_norms<<<4, 256, 0, stream>>>(dict, dictnorm);
    k_pack<<<256, 256, 0, stream>>>(dict, packB);
    k_vq<<<NROWS / RPB, 256, 0, stream>>>(x, dict, dictT, dictnorm, packB, out, block_sums);
    k_finalize<<<1, 1024, 0, stream>>>(block_sums, out + (size_t)NROWS * DIM);
}